// Round 10
// baseline (198.455 us; speedup 1.0000x reference)
//
#include <hip/hip_runtime.h>
#include <cfloat>

#define M_UP   32768
#define N_DOWN 8192
#define UPC    128
#define DOWNC  256
#define OUTC   128
#define NCHUNK 8
#define CHUNK  (N_DOWN / NCHUNK)   // 1024
#define G      8                   // selection group size
#define Q      2                   // queries per thread (amortizes LDS reads)
#define PG     12                  // padded group stride in floats (48B)

__device__ __forceinline__ void fma4(float4& acc, float s, const float4 w) {
    acc.x = fmaf(s, w.x, acc.x);
    acc.y = fmaf(s, w.y, acc.y);
    acc.z = fmaf(s, w.z, acc.z);
    acc.w = fmaf(s, w.w, acc.w);
}

// Branchless stable top-3 insert with index tracking.
// Strict < everywhere => earlier-inserted wins ties (stable in scan order),
// matching jax.lax.top_k's lower-index-first tie-break.
__device__ __forceinline__ void top3_bl(float s, int idx,
                                        float& d0, float& d1, float& d2,
                                        int& i0, int& i1, int& i2) {
    bool c0 = s < d0, c1 = s < d1, c2 = s < d2;
    float n0 = fminf(d0, s);
    float n1 = __builtin_amdgcn_fmed3f(d0, d1, s);
    float n2 = __builtin_amdgcn_fmed3f(d1, d2, s);
    int m0 = c0 ? idx : i0;
    int m1 = c0 ? i0 : (c1 ? idx : i1);
    int m2 = c1 ? i1 : (c2 ? idx : i2);
    d0 = n0; d1 = n1; d2 = n2;
    i0 = m0; i1 = m1; i2 = m2;
}

// ---------------------------------------------------------------------------
// K0: transpose weights for coalesced float4 GEMM reads.
// ---------------------------------------------------------------------------
__global__ __launch_bounds__(256) void transpose_w(
        const float* __restrict__ W_up, const float* __restrict__ W_down,
        float* __restrict__ wt_up, float* __restrict__ wt_down) {
    int e = blockIdx.x * 256 + threadIdx.x;
    if (e < DOWNC * OUTC) {
        int k = e >> 7, c = e & 127;
        wt_down[e] = W_down[c * DOWNC + k];
    } else {
        int e2 = e - DOWNC * OUTC;
        int k = e2 >> 7, c = e2 & 127;
        wt_up[e2] = W_up[c * UPC + k];
    }
}

// ---------------------------------------------------------------------------
// R9 register-blocked tile (kept for down_proj — proven).
// ---------------------------------------------------------------------------
template <int K>
__device__ __forceinline__ void gemm_tile32(
        const float* __restrict__ A, const float* __restrict__ WT,
        float* sA /*[32*36]*/, float* sW /*[32*128]*/,
        int rbase, int tid, float4 acc[2][2]) {
    const int rl = tid & 15;
    const int c0 = (tid >> 4) * 8;
    #pragma unroll 1
    for (int ph = 0; ph < K / 32; ++ph) {
        if (ph) __syncthreads();
        {
            int r = tid >> 3, k4 = tid & 7;
            float4 v = *(const float4*)(A + (size_t)(rbase + r) * K + ph * 32 + k4 * 4);
            *(float4*)&sA[r * 36 + k4 * 4] = v;
        }
        #pragma unroll
        for (int i = 0; i < 4; ++i) {
            int idx = tid + i * 256;
            int kk = idx >> 5, cc = idx & 31;
            float4 v = *(const float4*)(WT + (size_t)(ph * 32 + kk) * OUTC + cc * 4);
            *(float4*)&sW[kk * OUTC + cc * 4] = v;
        }
        __syncthreads();
        #pragma unroll 4
        for (int kk = 0; kk < 32; ++kk) {
            float a0 = sA[rl * 36 + kk];
            float a1 = sA[(rl + 16) * 36 + kk];
            float4 w0 = *(const float4*)&sW[kk * OUTC + c0];
            float4 w1 = *(const float4*)&sW[kk * OUTC + c0 + 4];
            fma4(acc[0][0], a0, w0); fma4(acc[0][1], a0, w1);
            fma4(acc[1][0], a1, w0); fma4(acc[1][1], a1, w1);
        }
    }
}

// ---------------------------------------------------------------------------
// K1: down_f = down_features @ W_down.T + b_down — unchanged R9 (proven).
// ---------------------------------------------------------------------------
__global__ __launch_bounds__(256) void down_proj(
        const float* __restrict__ A, const float* __restrict__ WT,
        const float* __restrict__ bias, float* __restrict__ down_f) {
    __shared__ __align__(16) float sA[32 * 36];
    __shared__ __align__(16) float sW[32 * OUTC];
    float4 acc[2][2] = {};
    gemm_tile32<DOWNC>(A, WT, sA, sW, blockIdx.x * 32, threadIdx.x, acc);
    const int rl = threadIdx.x & 15;
    const int cg = (threadIdx.x >> 4) * 2;
    const float4 b0 = ((const float4*)bias)[cg];
    const float4 b1 = ((const float4*)bias)[cg + 1];
    #pragma unroll
    for (int i = 0; i < 2; ++i) {
        const int row = blockIdx.x * 32 + rl + 16 * i;
        float4 v0 = acc[i][0], v1 = acc[i][1];
        v0.x += b0.x; v0.y += b0.y; v0.z += b0.z; v0.w += b0.w;
        v1.x += b1.x; v1.y += b1.y; v1.z += b1.z; v1.w += b1.w;
        ((float4*)down_f)[row * 32 + cg] = v0;
        ((float4*)down_f)[row * 32 + cg + 1] = v1;
    }
}

// ---------------------------------------------------------------------------
// K2: partial 3-NN — unchanged (proven 64us).
// ---------------------------------------------------------------------------
__global__ __launch_bounds__(256) void knn_partial(
        const float* __restrict__ up_points,
        const float* __restrict__ down_points,
        float2* __restrict__ part) {            // [NCHUNK][M_UP][3]
    __shared__ __align__(16) float sx[PG * (CHUNK / G)];
    __shared__ __align__(16) float sy[PG * (CHUNK / G)];
    __shared__ __align__(16) float sz[PG * (CHUNK / G)];
    const int base = blockIdx.y * CHUNK;
    for (int t = threadIdx.x; t < CHUNK; t += 256) {
        int g = base + t;
        int gi = t >> 3, j = t & 7;
        sx[PG * gi + j] = down_points[3 * g];
        sy[PG * gi + j] = down_points[3 * g + 1];
        sz[PG * gi + j] = down_points[3 * g + 2];
    }
    __syncthreads();

    const int m0 = blockIdx.x * (256 * Q) + threadIdx.x;
    const int m1 = m0 + 256;
    const float q0x = up_points[3 * m0];
    const float q0y = up_points[3 * m0 + 1];
    const float q0z = up_points[3 * m0 + 2];
    const float q1x = up_points[3 * m1];
    const float q1y = up_points[3 * m1 + 1];
    const float q1z = up_points[3 * m1 + 2];

    float a_gd0 = FLT_MAX, a_gd1 = FLT_MAX, a_gd2 = FLT_MAX;
    int   a_gi0 = 0, a_gi1 = 0, a_gi2 = 0;
    float b_gd0 = FLT_MAX, b_gd1 = FLT_MAX, b_gd2 = FLT_MAX;
    int   b_gi0 = 0, b_gi1 = 0, b_gi2 = 0;

    for (int gi = 0; gi < CHUNK / G; ++gi) {
        float4 x0 = *(const float4*)&sx[PG * gi], x1 = *(const float4*)&sx[PG * gi + 4];
        float4 y0 = *(const float4*)&sy[PG * gi], y1 = *(const float4*)&sy[PG * gi + 4];
        float4 z0 = *(const float4*)&sz[PG * gi], z1 = *(const float4*)&sz[PG * gi + 4];
        float px[G] = {x0.x, x0.y, x0.z, x0.w, x1.x, x1.y, x1.z, x1.w};
        float py[G] = {y0.x, y0.y, y0.z, y0.w, y1.x, y1.y, y1.z, y1.w};
        float pz[G] = {z0.x, z0.y, z0.z, z0.w, z1.x, z1.y, z1.z, z1.w};
        float s0[G], s1[G];
        #pragma unroll
        for (int j = 0; j < G; ++j) {
            float dx0 = q0x - px[j], dy0 = q0y - py[j], dz0 = q0z - pz[j];
            s0[j] = fmaf(dz0, dz0, fmaf(dy0, dy0, dx0 * dx0));
            float dx1 = q1x - px[j], dy1 = q1y - py[j], dz1 = q1z - pz[j];
            s1[j] = fmaf(dz1, dz1, fmaf(dy1, dy1, dx1 * dx1));
        }
        float gm0 = fminf(fminf(fminf(s0[0], s0[1]), fminf(s0[2], s0[3])),
                          fminf(fminf(s0[4], s0[5]), fminf(s0[6], s0[7])));
        float gm1 = fminf(fminf(fminf(s1[0], s1[1]), fminf(s1[2], s1[3])),
                          fminf(fminf(s1[4], s1[5]), fminf(s1[6], s1[7])));
        top3_bl(gm0, gi, a_gd0, a_gd1, a_gd2, a_gi0, a_gi1, a_gi2);
        top3_bl(gm1, gi, b_gd0, b_gd1, b_gd2, b_gi0, b_gi1, b_gi2);
    }

    #pragma unroll
    for (int qq = 0; qq < Q; ++qq) {
        const float qx = qq ? q1x : q0x;
        const float qy = qq ? q1y : q0y;
        const float qz = qq ? q1z : q0z;
        int bases[3];
        if (qq == 0) { bases[0] = a_gi0; bases[1] = a_gi1; bases[2] = a_gi2; }
        else         { bases[0] = b_gi0; bases[1] = b_gi1; bases[2] = b_gi2; }
        float D0 = FLT_MAX, D1 = FLT_MAX, D2 = FLT_MAX;
        int I0 = 0, I1 = 0, I2 = 0;
        #pragma unroll
        for (int t = 0; t < 3; ++t) {
            const int gb = bases[t];
            float4 x0 = *(const float4*)&sx[PG * gb], x1 = *(const float4*)&sx[PG * gb + 4];
            float4 y0 = *(const float4*)&sy[PG * gb], y1 = *(const float4*)&sy[PG * gb + 4];
            float4 z0 = *(const float4*)&sz[PG * gb], z1 = *(const float4*)&sz[PG * gb + 4];
            float px[G] = {x0.x, x0.y, x0.z, x0.w, x1.x, x1.y, x1.z, x1.w};
            float py[G] = {y0.x, y0.y, y0.z, y0.w, y1.x, y1.y, y1.z, y1.w};
            float pz[G] = {z0.x, z0.y, z0.z, z0.w, z1.x, z1.y, z1.z, z1.w};
            #pragma unroll
            for (int j = 0; j < G; ++j) {
                float dx = qx - px[j], dy = qy - py[j], dz = qz - pz[j];
                float s = fmaf(dz, dz, fmaf(dy, dy, dx * dx));
                top3_bl(s, base + gb * G + j, D0, D1, D2, I0, I1, I2);
            }
        }
        const int m = qq ? m1 : m0;
        const int o = (blockIdx.y * M_UP + m) * 3;
        part[o]     = make_float2(D0, __int_as_float(I0));
        part[o + 1] = make_float2(D1, __int_as_float(I1));
        part[o + 2] = make_float2(D2, __int_as_float(I2));
    }
}

// ---------------------------------------------------------------------------
// Per-row epilogue for up_fused: top-3 merge + gather + interp + store.
// Called with statically-indexed acc registers (rule: no runtime acc index).
// ---------------------------------------------------------------------------
__device__ __forceinline__ void up_row_epilogue(
        int m, int ct, float4 a0, float4 a1,
        const float4 b0, const float4 b1,
        const float2* __restrict__ part, const float4* __restrict__ df4,
        float4* __restrict__ out4) {
    float D0 = FLT_MAX, D1 = FLT_MAX, D2 = FLT_MAX;
    int I0 = 0, I1 = 0, I2 = 0;
    #pragma unroll
    for (int s = 0; s < NCHUNK; ++s) {
        const float2* p = part + ((size_t)s * M_UP + m) * 3;
        float2 v0 = p[0], v1 = p[1], v2 = p[2];
        top3_bl(v0.x, __float_as_int(v0.y), D0, D1, D2, I0, I1, I2);
        top3_bl(v1.x, __float_as_int(v1.y), D0, D1, D2, I0, I1, I2);
        top3_bl(v2.x, __float_as_int(v2.y), D0, D1, D2, I0, I1, I2);
    }
    float r0 = 1.f / (D0 + 1e-8f);
    float r1 = 1.f / (D1 + 1e-8f);
    float r2 = 1.f / (D2 + 1e-8f);
    float rs = (r0 + r1) + r2;
    float w0 = r0 / rs, w1 = r1 / rs, w2 = r2 / rs;
    float4 f00 = df4[I0 * 32 + ct],      f01 = df4[I0 * 32 + ct + 16];
    float4 f10 = df4[I1 * 32 + ct],      f11 = df4[I1 * 32 + ct + 16];
    float4 f20 = df4[I2 * 32 + ct],      f21 = df4[I2 * 32 + ct + 16];
    float4 res0, res1;
    res0.x = a0.x + b0.x + fmaf(w0, f00.x, fmaf(w1, f10.x, w2 * f20.x));
    res0.y = a0.y + b0.y + fmaf(w0, f00.y, fmaf(w1, f10.y, w2 * f20.y));
    res0.z = a0.z + b0.z + fmaf(w0, f00.z, fmaf(w1, f10.z, w2 * f20.z));
    res0.w = a0.w + b0.w + fmaf(w0, f00.w, fmaf(w1, f10.w, w2 * f20.w));
    res1.x = a1.x + b1.x + fmaf(w0, f01.x, fmaf(w1, f11.x, w2 * f21.x));
    res1.y = a1.y + b1.y + fmaf(w0, f01.y, fmaf(w1, f11.y, w2 * f21.y));
    res1.z = a1.z + b1.z + fmaf(w0, f01.z, fmaf(w1, f11.z, w2 * f21.z));
    res1.w = a1.w + b1.w + fmaf(w0, f01.w, fmaf(w1, f11.w, w2 * f21.w));
    out4[m * 32 + ct] = res0;
    out4[m * 32 + ct + 16] = res1;
}

// ---------------------------------------------------------------------------
// K3: fused up-projection + top-3 merge + interpolation + bias + add.
// R10: 128x128 block tile, per-thread 8 rows x 8 cols (acc=64f). Intensity
// 1.0 B/FMA-lane vs the per-CU LDS pipe's ~1.33 B/lane/cy supply -> k-loop
// ~10us (R9's 2x8 tile was 2.25 B/FMA -> 31us LDS-bound). A stored
// TRANSPOSED in LDS so a thread's 8 rows are contiguous (2 b128/k); W cols
// split ct*4 / 64+ct*4 so both reads are 2-way bank-aliased (free, m136).
// Grid 256 = 1 block/CU; launch_bounds(256,1) -> no spill possible.
// Epilogue: 8 explicit row calls + sched_barrier(0) fences (bounds regs).
// ---------------------------------------------------------------------------
__global__ __launch_bounds__(256, 1) void up_fused(
        const float* __restrict__ A, const float* __restrict__ WT,
        const float* __restrict__ bias, const float* __restrict__ down_f,
        const float2* __restrict__ part,
        float* __restrict__ out) {
    __shared__ __align__(16) float sAT[32][128];    // [k][row] transposed, 16KB
    __shared__ __align__(16) float sW[32][128];     // [k][col], 16KB
    const int tid = threadIdx.x;
    const int rt8 = (tid >> 4) * 8;                 // first of 8 rows
    const int ct  = tid & 15;                       // col float4 index
    const int ct4 = ct * 4;                         // first of 4 cols (lo half)
    const int rbase = blockIdx.x * 128;

    float4 acc[8][2] = {};
    #pragma unroll 1
    for (int ph = 0; ph < UPC / 32; ++ph) {
        if (ph) __syncthreads();
        {   // stage A transposed: 2 threads/row, 4 float4 each
            int r = tid >> 1;
            int kb = (tid & 1) * 16;
            const float* Ar = A + (size_t)(rbase + r) * UPC + ph * 32 + kb;
            #pragma unroll
            for (int i = 0; i < 4; ++i) {
                float4 v = *(const float4*)(Ar + i * 4);
                int k0 = kb + i * 4;
                sAT[k0][r] = v.x; sAT[k0 + 1][r] = v.y;
                sAT[k0 + 2][r] = v.z; sAT[k0 + 3][r] = v.w;
            }
        }
        {   // stage W: contiguous float4 copies
            const float4* Wp = (const float4*)(WT + (size_t)ph * 32 * OUTC);
            float4* sW4 = (float4*)&sW[0][0];
            #pragma unroll
            for (int i = 0; i < 4; ++i)
                sW4[tid + i * 256] = Wp[tid + i * 256];
        }
        __syncthreads();
        #pragma unroll 4
        for (int kk = 0; kk < 32; ++kk) {
            float4 aLo = *(const float4*)&sAT[kk][rt8];
            float4 aHi = *(const float4*)&sAT[kk][rt8 + 4];
            float4 w0  = *(const float4*)&sW[kk][ct4];
            float4 w1  = *(const float4*)&sW[kk][64 + ct4];
            fma4(acc[0][0], aLo.x, w0); fma4(acc[0][1], aLo.x, w1);
            fma4(acc[1][0], aLo.y, w0); fma4(acc[1][1], aLo.y, w1);
            fma4(acc[2][0], aLo.z, w0); fma4(acc[2][1], aLo.z, w1);
            fma4(acc[3][0], aLo.w, w0); fma4(acc[3][1], aLo.w, w1);
            fma4(acc[4][0], aHi.x, w0); fma4(acc[4][1], aHi.x, w1);
            fma4(acc[5][0], aHi.y, w0); fma4(acc[5][1], aHi.y, w1);
            fma4(acc[6][0], aHi.z, w0); fma4(acc[6][1], aHi.z, w1);
            fma4(acc[7][0], aHi.w, w0); fma4(acc[7][1], aHi.w, w1);
        }
    }

    const float4 b0 = ((const float4*)bias)[ct];
    const float4 b1 = ((const float4*)bias)[ct + 16];
    const float4* df4 = (const float4*)down_f;
    float4* out4 = (float4*)out;
    const int m0 = rbase + rt8;
    up_row_epilogue(m0 + 0, ct, acc[0][0], acc[0][1], b0, b1, part, df4, out4);
    __builtin_amdgcn_sched_barrier(0);
    up_row_epilogue(m0 + 1, ct, acc[1][0], acc[1][1], b0, b1, part, df4, out4);
    __builtin_amdgcn_sched_barrier(0);
    up_row_epilogue(m0 + 2, ct, acc[2][0], acc[2][1], b0, b1, part, df4, out4);
    __builtin_amdgcn_sched_barrier(0);
    up_row_epilogue(m0 + 3, ct, acc[3][0], acc[3][1], b0, b1, part, df4, out4);
    __builtin_amdgcn_sched_barrier(0);
    up_row_epilogue(m0 + 4, ct, acc[4][0], acc[4][1], b0, b1, part, df4, out4);
    __builtin_amdgcn_sched_barrier(0);
    up_row_epilogue(m0 + 5, ct, acc[5][0], acc[5][1], b0, b1, part, df4, out4);
    __builtin_amdgcn_sched_barrier(0);
    up_row_epilogue(m0 + 6, ct, acc[6][0], acc[6][1], b0, b1, part, df4, out4);
    __builtin_amdgcn_sched_barrier(0);
    up_row_epilogue(m0 + 7, ct, acc[7][0], acc[7][1], b0, b1, part, df4, out4);
}

extern "C" void kernel_launch(void* const* d_in, const int* in_sizes, int n_in,
                              void* d_out, int out_size, void* d_ws, size_t ws_size,
                              hipStream_t stream) {
    const float* up_points     = (const float*)d_in[0];
    const float* up_features   = (const float*)d_in[1];
    const float* down_points   = (const float*)d_in[2];
    const float* down_features = (const float*)d_in[3];
    const float* W_up          = (const float*)d_in[4];
    const float* b_up          = (const float*)d_in[5];
    const float* W_down        = (const float*)d_in[6];
    const float* b_down        = (const float*)d_in[7];
    float* out = (float*)d_out;

    float* wt_down = (float*)d_ws;                         // 256*128
    float* wt_up   = wt_down + DOWNC * OUTC;               // 128*128
    float* down_f  = wt_up + UPC * OUTC;                   // 8192*128
    float2* part   = (float2*)(down_f + N_DOWN * OUTC);    // NCHUNK*32768*3 float2
    // total ~10.7 MB (proven footprint)

    transpose_w<<<(DOWNC * OUTC + UPC * OUTC) / 256, 256, 0, stream>>>(
        W_up, W_down, wt_up, wt_down);
    down_proj<<<N_DOWN / 32, 256, 0, stream>>>(
        down_features, wt_down, b_down, down_f);
    knn_partial<<<dim3(M_UP / (256 * Q), NCHUNK), 256, 0, stream>>>(
        up_points, down_points, part);
    up_fused<<<M_UP / 128, 256, 0, stream>>>(
        up_features, wt_up, b_up, down_f, part, out);
}

// Round 11
// 173.817 us; speedup vs baseline: 1.1417x; 1.1417x over previous
//
#include <hip/hip_runtime.h>
#include <cfloat>

#define M_UP   32768
#define N_DOWN 8192
#define UPC    128
#define DOWNC  256
#define OUTC   128
#define NCHUNK 8
#define CHUNK  (N_DOWN / NCHUNK)   // 1024
#define G      8                   // selection group size
#define Q      2                   // queries per thread (amortizes LDS reads)
#define PG     12                  // padded group stride in floats (48B)

__device__ __forceinline__ void fma4(float4& acc, float s, const float4 w) {
    acc.x = fmaf(s, w.x, acc.x);
    acc.y = fmaf(s, w.y, acc.y);
    acc.z = fmaf(s, w.z, acc.z);
    acc.w = fmaf(s, w.w, acc.w);
}

// Branchless stable top-3 insert with index tracking.
// Strict < everywhere => earlier-inserted wins ties (stable in scan order),
// matching jax.lax.top_k's lower-index-first tie-break.
__device__ __forceinline__ void top3_bl(float s, int idx,
                                        float& d0, float& d1, float& d2,
                                        int& i0, int& i1, int& i2) {
    bool c0 = s < d0, c1 = s < d1, c2 = s < d2;
    float n0 = fminf(d0, s);
    float n1 = __builtin_amdgcn_fmed3f(d0, d1, s);
    float n2 = __builtin_amdgcn_fmed3f(d1, d2, s);
    int m0 = c0 ? idx : i0;
    int m1 = c0 ? i0 : (c1 ? idx : i1);
    int m2 = c1 ? i1 : (c2 ? idx : i2);
    d0 = n0; d1 = n1; d2 = n2;
    i0 = m0; i1 = m1; i2 = m2;
}

// ---------------------------------------------------------------------------
// K0: transpose weights for coalesced float4 GEMM reads.
// ---------------------------------------------------------------------------
__global__ __launch_bounds__(256) void transpose_w(
        const float* __restrict__ W_up, const float* __restrict__ W_down,
        float* __restrict__ wt_up, float* __restrict__ wt_down) {
    int e = blockIdx.x * 256 + threadIdx.x;
    if (e < DOWNC * OUTC) {
        int k = e >> 7, c = e & 127;
        wt_down[e] = W_down[c * DOWNC + k];
    } else {
        int e2 = e - DOWNC * OUTC;
        int k = e2 >> 7, c = e2 & 127;
        wt_up[e2] = W_up[c * UPC + k];
    }
}

// ---------------------------------------------------------------------------
// R9 register-blocked GEMM tile (proven): 32 rows x 128 cols, 256 threads,
// per-thread 2 rows x 8 cols.
// ---------------------------------------------------------------------------
template <int K>
__device__ __forceinline__ void gemm_tile32(
        const float* __restrict__ A, const float* __restrict__ WT,
        float* sA /*[32*36]*/, float* sW /*[32*128]*/,
        int rbase, int tid, float4 acc[2][2]) {
    const int rl = tid & 15;
    const int c0 = (tid >> 4) * 8;
    #pragma unroll 1
    for (int ph = 0; ph < K / 32; ++ph) {
        if (ph) __syncthreads();
        {
            int r = tid >> 3, k4 = tid & 7;
            float4 v = *(const float4*)(A + (size_t)(rbase + r) * K + ph * 32 + k4 * 4);
            *(float4*)&sA[r * 36 + k4 * 4] = v;
        }
        #pragma unroll
        for (int i = 0; i < 4; ++i) {
            int idx = tid + i * 256;
            int kk = idx >> 5, cc = idx & 31;
            float4 v = *(const float4*)(WT + (size_t)(ph * 32 + kk) * OUTC + cc * 4);
            *(float4*)&sW[kk * OUTC + cc * 4] = v;
        }
        __syncthreads();
        #pragma unroll 4
        for (int kk = 0; kk < 32; ++kk) {
            float a0 = sA[rl * 36 + kk];
            float a1 = sA[(rl + 16) * 36 + kk];
            float4 w0 = *(const float4*)&sW[kk * OUTC + c0];
            float4 w1 = *(const float4*)&sW[kk * OUTC + c0 + 4];
            fma4(acc[0][0], a0, w0); fma4(acc[0][1], a0, w1);
            fma4(acc[1][0], a1, w0); fma4(acc[1][1], a1, w1);
        }
    }
}

// ---------------------------------------------------------------------------
// down_proj body (verbatim R9 logic, shared mem passed in).
// ---------------------------------------------------------------------------
__device__ __forceinline__ void down_body(
        const float* __restrict__ A, const float* __restrict__ WT,
        const float* __restrict__ bias, float* __restrict__ down_f,
        int rb, int tid, float* smem) {
    float* sA = smem;            // 32*36 = 1152 floats
    float* sW = smem + 1152;     // 32*128 = 4096 floats
    float4 acc[2][2] = {};
    gemm_tile32<DOWNC>(A, WT, sA, sW, rb * 32, tid, acc);
    const int rl = tid & 15;
    const int cg = (tid >> 4) * 2;
    const float4 b0 = ((const float4*)bias)[cg];
    const float4 b1 = ((const float4*)bias)[cg + 1];
    #pragma unroll
    for (int i = 0; i < 2; ++i) {
        const int row = rb * 32 + rl + 16 * i;
        float4 v0 = acc[i][0], v1 = acc[i][1];
        v0.x += b0.x; v0.y += b0.y; v0.z += b0.z; v0.w += b0.w;
        v1.x += b1.x; v1.y += b1.y; v1.z += b1.z; v1.w += b1.w;
        ((float4*)down_f)[row * 32 + cg] = v0;
        ((float4*)down_f)[row * 32 + cg + 1] = v1;
    }
}

// ---------------------------------------------------------------------------
// knn body (verbatim R9 logic, shared mem passed in).
// ---------------------------------------------------------------------------
__device__ __forceinline__ void knn_body(
        const float* __restrict__ up_points,
        const float* __restrict__ down_points,
        float2* __restrict__ part,
        int bx, int by, int tid, float* smem) {
    float* sx = smem;            // PG*128 = 1536
    float* sy = smem + 1536;
    float* sz = smem + 3072;
    const int base = by * CHUNK;
    for (int t = tid; t < CHUNK; t += 256) {
        int g = base + t;
        int gi = t >> 3, j = t & 7;
        sx[PG * gi + j] = down_points[3 * g];
        sy[PG * gi + j] = down_points[3 * g + 1];
        sz[PG * gi + j] = down_points[3 * g + 2];
    }
    __syncthreads();

    const int m0 = bx * (256 * Q) + tid;
    const int m1 = m0 + 256;
    const float q0x = up_points[3 * m0];
    const float q0y = up_points[3 * m0 + 1];
    const float q0z = up_points[3 * m0 + 2];
    const float q1x = up_points[3 * m1];
    const float q1y = up_points[3 * m1 + 1];
    const float q1z = up_points[3 * m1 + 2];

    float a_gd0 = FLT_MAX, a_gd1 = FLT_MAX, a_gd2 = FLT_MAX;
    int   a_gi0 = 0, a_gi1 = 0, a_gi2 = 0;
    float b_gd0 = FLT_MAX, b_gd1 = FLT_MAX, b_gd2 = FLT_MAX;
    int   b_gi0 = 0, b_gi1 = 0, b_gi2 = 0;

    for (int gi = 0; gi < CHUNK / G; ++gi) {
        float4 x0 = *(const float4*)&sx[PG * gi], x1 = *(const float4*)&sx[PG * gi + 4];
        float4 y0 = *(const float4*)&sy[PG * gi], y1 = *(const float4*)&sy[PG * gi + 4];
        float4 z0 = *(const float4*)&sz[PG * gi], z1 = *(const float4*)&sz[PG * gi + 4];
        float px[G] = {x0.x, x0.y, x0.z, x0.w, x1.x, x1.y, x1.z, x1.w};
        float py[G] = {y0.x, y0.y, y0.z, y0.w, y1.x, y1.y, y1.z, y1.w};
        float pz[G] = {z0.x, z0.y, z0.z, z0.w, z1.x, z1.y, z1.z, z1.w};
        float s0[G], s1[G];
        #pragma unroll
        for (int j = 0; j < G; ++j) {
            float dx0 = q0x - px[j], dy0 = q0y - py[j], dz0 = q0z - pz[j];
            s0[j] = fmaf(dz0, dz0, fmaf(dy0, dy0, dx0 * dx0));
            float dx1 = q1x - px[j], dy1 = q1y - py[j], dz1 = q1z - pz[j];
            s1[j] = fmaf(dz1, dz1, fmaf(dy1, dy1, dx1 * dx1));
        }
        float gm0 = fminf(fminf(fminf(s0[0], s0[1]), fminf(s0[2], s0[3])),
                          fminf(fminf(s0[4], s0[5]), fminf(s0[6], s0[7])));
        float gm1 = fminf(fminf(fminf(s1[0], s1[1]), fminf(s1[2], s1[3])),
                          fminf(fminf(s1[4], s1[5]), fminf(s1[6], s1[7])));
        top3_bl(gm0, gi, a_gd0, a_gd1, a_gd2, a_gi0, a_gi1, a_gi2);
        top3_bl(gm1, gi, b_gd0, b_gd1, b_gd2, b_gi0, b_gi1, b_gi2);
    }

    // exact refine over the 3 winning groups (24 points per query)
    #pragma unroll
    for (int qq = 0; qq < Q; ++qq) {
        const float qx = qq ? q1x : q0x;
        const float qy = qq ? q1y : q0y;
        const float qz = qq ? q1z : q0z;
        int bases[3];
        if (qq == 0) { bases[0] = a_gi0; bases[1] = a_gi1; bases[2] = a_gi2; }
        else         { bases[0] = b_gi0; bases[1] = b_gi1; bases[2] = b_gi2; }
        float D0 = FLT_MAX, D1 = FLT_MAX, D2 = FLT_MAX;
        int I0 = 0, I1 = 0, I2 = 0;
        #pragma unroll
        for (int t = 0; t < 3; ++t) {
            const int gb = bases[t];
            float4 x0 = *(const float4*)&sx[PG * gb], x1 = *(const float4*)&sx[PG * gb + 4];
            float4 y0 = *(const float4*)&sy[PG * gb], y1 = *(const float4*)&sy[PG * gb + 4];
            float4 z0 = *(const float4*)&sz[PG * gb], z1 = *(const float4*)&sz[PG * gb + 4];
            float px[G] = {x0.x, x0.y, x0.z, x0.w, x1.x, x1.y, x1.z, x1.w};
            float py[G] = {y0.x, y0.y, y0.z, y0.w, y1.x, y1.y, y1.z, y1.w};
            float pz[G] = {z0.x, z0.y, z0.z, z0.w, z1.x, z1.y, z1.z, z1.w};
            #pragma unroll
            for (int j = 0; j < G; ++j) {
                float dx = qx - px[j], dy = qy - py[j], dz = qz - pz[j];
                float s = fmaf(dz, dz, fmaf(dy, dy, dx * dx));
                top3_bl(s, base + gb * G + j, D0, D1, D2, I0, I1, I2);
            }
        }
        const int m = qq ? m1 : m0;
        const int o = (by * M_UP + m) * 3;
        part[o]     = make_float2(D0, __int_as_float(I0));
        part[o + 1] = make_float2(D1, __int_as_float(I1));
        part[o + 2] = make_float2(D2, __int_as_float(I2));
    }
}

// ---------------------------------------------------------------------------
// K1+K2 fused: down_proj and knn_partial are data-independent; serial launch
// left each LDS/latency-bound at <50%/65% pipe utilization (R9 accounting:
// knn 64us + down ~45us serial). One kernel, role by blockIdx.x: 512 knn
// blocks + 256 down blocks = 3 blocks/CU mixed -> down-role waves fill the
// issue slots knn's latency-bound scan leaves idle. Combined LDS-pipe work
// ~149 kcy/CU ~= 62us floor. Bodies are verbatim the proven R9 kernels.
// ---------------------------------------------------------------------------
__global__ __launch_bounds__(256) void fused_dp_knn(
        const float* __restrict__ down_features, const float* __restrict__ wt_down,
        const float* __restrict__ b_down, float* __restrict__ down_f,
        const float* __restrict__ up_points, const float* __restrict__ down_points,
        float2* __restrict__ part) {
    __shared__ __align__(16) float smem[5248];   // max(knn 4608, down 5248) floats
    const int bid = blockIdx.x;
    if (bid < 512) {
        knn_body(up_points, down_points, part, bid & 63, bid >> 6,
                 threadIdx.x, smem);
    } else {
        down_body(down_features, wt_down, b_down, down_f, bid - 512,
                  threadIdx.x, smem);
    }
}

// ---------------------------------------------------------------------------
// K3: fused up-projection + top-3 merge + interpolation + bias + add.
// Exact R9 version (best measured configuration).
// ---------------------------------------------------------------------------
__global__ __launch_bounds__(256) void up_fused(
        const float* __restrict__ A, const float* __restrict__ WT,
        const float* __restrict__ bias, const float* __restrict__ down_f,
        const float2* __restrict__ part,
        float* __restrict__ out) {
    __shared__ __align__(16) float sA[32 * 36];
    __shared__ __align__(16) float sW[32 * OUTC];
    float4 acc[2][2] = {};
    gemm_tile32<UPC>(A, WT, sA, sW, blockIdx.x * 32, threadIdx.x, acc);

    const int rl = threadIdx.x & 15;
    const int cg = (threadIdx.x >> 4) * 2;       // col float4 index
    const float4 b0 = ((const float4*)bias)[cg];
    const float4 b1 = ((const float4*)bias)[cg + 1];
    const float4* df4 = (const float4*)down_f;
    #pragma unroll
    for (int i = 0; i < 2; ++i) {
        const int m = blockIdx.x * 32 + rl + 16 * i;
        float D0 = FLT_MAX, D1 = FLT_MAX, D2 = FLT_MAX;
        int I0 = 0, I1 = 0, I2 = 0;
        #pragma unroll
        for (int s = 0; s < NCHUNK; ++s) {
            const float2* p = part + ((size_t)s * M_UP + m) * 3;
            #pragma unroll
            for (int j = 0; j < 3; ++j) {
                float2 v = p[j];
                top3_bl(v.x, __float_as_int(v.y), D0, D1, D2, I0, I1, I2);
            }
        }
        float r0 = 1.f / (D0 + 1e-8f);
        float r1 = 1.f / (D1 + 1e-8f);
        float r2 = 1.f / (D2 + 1e-8f);
        float rs = (r0 + r1) + r2;
        float w0 = r0 / rs, w1 = r1 / rs, w2 = r2 / rs;
        float4 f00 = df4[I0 * 32 + cg],     f01 = df4[I0 * 32 + cg + 1];
        float4 f10 = df4[I1 * 32 + cg],     f11 = df4[I1 * 32 + cg + 1];
        float4 f20 = df4[I2 * 32 + cg],     f21 = df4[I2 * 32 + cg + 1];
        float4 v0 = acc[i][0], v1 = acc[i][1];
        float4 res0, res1;
        res0.x = v0.x + b0.x + fmaf(w0, f00.x, fmaf(w1, f10.x, w2 * f20.x));
        res0.y = v0.y + b0.y + fmaf(w0, f00.y, fmaf(w1, f10.y, w2 * f20.y));
        res0.z = v0.z + b0.z + fmaf(w0, f00.z, fmaf(w1, f10.z, w2 * f20.z));
        res0.w = v0.w + b0.w + fmaf(w0, f00.w, fmaf(w1, f10.w, w2 * f20.w));
        res1.x = v1.x + b1.x + fmaf(w0, f01.x, fmaf(w1, f11.x, w2 * f21.x));
        res1.y = v1.y + b1.y + fmaf(w0, f01.y, fmaf(w1, f11.y, w2 * f21.y));
        res1.z = v1.z + b1.z + fmaf(w0, f01.z, fmaf(w1, f11.z, w2 * f21.z));
        res1.w = v1.w + b1.w + fmaf(w0, f01.w, fmaf(w1, f11.w, w2 * f21.w));
        ((float4*)out)[m * 32 + cg] = res0;
        ((float4*)out)[m * 32 + cg + 1] = res1;
    }
}

extern "C" void kernel_launch(void* const* d_in, const int* in_sizes, int n_in,
                              void* d_out, int out_size, void* d_ws, size_t ws_size,
                              hipStream_t stream) {
    const float* up_points     = (const float*)d_in[0];
    const float* up_features   = (const float*)d_in[1];
    const float* down_points   = (const float*)d_in[2];
    const float* down_features = (const float*)d_in[3];
    const float* W_up          = (const float*)d_in[4];
    const float* b_up          = (const float*)d_in[5];
    const float* W_down        = (const float*)d_in[6];
    const float* b_down        = (const float*)d_in[7];
    float* out = (float*)d_out;

    float* wt_down = (float*)d_ws;                         // 256*128
    float* wt_up   = wt_down + DOWNC * OUTC;               // 128*128
    float* down_f  = wt_up + UPC * OUTC;                   // 8192*128
    float2* part   = (float2*)(down_f + N_DOWN * OUTC);    // NCHUNK*32768*3 float2
    // total ~10.7 MB (proven footprint)

    transpose_w<<<(DOWNC * OUTC + UPC * OUTC) / 256, 256, 0, stream>>>(
        W_up, W_down, wt_up, wt_down);
    fused_dp_knn<<<768, 256, 0, stream>>>(
        down_features, wt_down, b_down, down_f, up_points, down_points, part);
    up_fused<<<M_UP / 32, 256, 0, stream>>>(
        up_features, wt_up, b_up, down_f, part, out);
}

// Round 12
// 167.928 us; speedup vs baseline: 1.1818x; 1.0351x over previous
//
#include <hip/hip_runtime.h>
#include <cfloat>

#define M_UP   32768
#define N_DOWN 8192
#define UPC    128
#define DOWNC  256
#define OUTC   128
#define NCHUNK 8
#define CHUNK  (N_DOWN / NCHUNK)   // 1024
#define G      8                   // selection group size
#define Q      2                   // queries per thread (amortizes LDS reads)
#define PG     12                  // padded group stride in floats (48B)

__device__ __forceinline__ void fma4(float4& acc, float s, const float4 w) {
    acc.x = fmaf(s, w.x, acc.x);
    acc.y = fmaf(s, w.y, acc.y);
    acc.z = fmaf(s, w.z, acc.z);
    acc.w = fmaf(s, w.w, acc.w);
}

// Branchless stable top-3 insert with index tracking.
// Strict < everywhere => earlier-inserted wins ties (stable in scan order),
// matching jax.lax.top_k's lower-index-first tie-break.
__device__ __forceinline__ void top3_bl(float s, int idx,
                                        float& d0, float& d1, float& d2,
                                        int& i0, int& i1, int& i2) {
    bool c0 = s < d0, c1 = s < d1, c2 = s < d2;
    float n0 = fminf(d0, s);
    float n1 = __builtin_amdgcn_fmed3f(d0, d1, s);
    float n2 = __builtin_amdgcn_fmed3f(d1, d2, s);
    int m0 = c0 ? idx : i0;
    int m1 = c0 ? i0 : (c1 ? idx : i1);
    int m2 = c1 ? i1 : (c2 ? idx : i2);
    d0 = n0; d1 = n1; d2 = n2;
    i0 = m0; i1 = m1; i2 = m2;
}

// ---------------------------------------------------------------------------
// K0: transpose weights for coalesced float4 GEMM reads.
// ---------------------------------------------------------------------------
__global__ __launch_bounds__(256) void transpose_w(
        const float* __restrict__ W_up, const float* __restrict__ W_down,
        float* __restrict__ wt_up, float* __restrict__ wt_down) {
    int e = blockIdx.x * 256 + threadIdx.x;
    if (e < DOWNC * OUTC) {
        int k = e >> 7, c = e & 127;
        wt_down[e] = W_down[c * DOWNC + k];
    } else {
        int e2 = e - DOWNC * OUTC;
        int k = e2 >> 7, c = e2 & 127;
        wt_up[e2] = W_up[c * UPC + k];
    }
}

// ---------------------------------------------------------------------------
// R9 register-blocked GEMM tile (used by down-role; proven).
// ---------------------------------------------------------------------------
template <int K>
__device__ __forceinline__ void gemm_tile32(
        const float* __restrict__ A, const float* __restrict__ WT,
        float* sA /*[32*36]*/, float* sW /*[32*128]*/,
        int rbase, int tid, float4 acc[2][2]) {
    const int rl = tid & 15;
    const int c0 = (tid >> 4) * 8;
    #pragma unroll 1
    for (int ph = 0; ph < K / 32; ++ph) {
        if (ph) __syncthreads();
        {
            int r = tid >> 3, k4 = tid & 7;
            float4 v = *(const float4*)(A + (size_t)(rbase + r) * K + ph * 32 + k4 * 4);
            *(float4*)&sA[r * 36 + k4 * 4] = v;
        }
        #pragma unroll
        for (int i = 0; i < 4; ++i) {
            int idx = tid + i * 256;
            int kk = idx >> 5, cc = idx & 31;
            float4 v = *(const float4*)(WT + (size_t)(ph * 32 + kk) * OUTC + cc * 4);
            *(float4*)&sW[kk * OUTC + cc * 4] = v;
        }
        __syncthreads();
        #pragma unroll 4
        for (int kk = 0; kk < 32; ++kk) {
            float a0 = sA[rl * 36 + kk];
            float a1 = sA[(rl + 16) * 36 + kk];
            float4 w0 = *(const float4*)&sW[kk * OUTC + c0];
            float4 w1 = *(const float4*)&sW[kk * OUTC + c0 + 4];
            fma4(acc[0][0], a0, w0); fma4(acc[0][1], a0, w1);
            fma4(acc[1][0], a1, w0); fma4(acc[1][1], a1, w1);
        }
    }
}

// ---------------------------------------------------------------------------
// down_proj body (verbatim — proven inside fused_dp_knn).
// ---------------------------------------------------------------------------
__device__ __forceinline__ void down_body(
        const float* __restrict__ A, const float* __restrict__ WT,
        const float* __restrict__ bias, float* __restrict__ down_f,
        int rb, int tid, float* smem) {
    float* sA = smem;            // 32*36 = 1152 floats
    float* sW = smem + 1152;     // 32*128 = 4096 floats
    float4 acc[2][2] = {};
    gemm_tile32<DOWNC>(A, WT, sA, sW, rb * 32, tid, acc);
    const int rl = tid & 15;
    const int cg = (tid >> 4) * 2;
    const float4 b0 = ((const float4*)bias)[cg];
    const float4 b1 = ((const float4*)bias)[cg + 1];
    #pragma unroll
    for (int i = 0; i < 2; ++i) {
        const int row = rb * 32 + rl + 16 * i;
        float4 v0 = acc[i][0], v1 = acc[i][1];
        v0.x += b0.x; v0.y += b0.y; v0.z += b0.z; v0.w += b0.w;
        v1.x += b1.x; v1.y += b1.y; v1.z += b1.z; v1.w += b1.w;
        ((float4*)down_f)[row * 32 + cg] = v0;
        ((float4*)down_f)[row * 32 + cg + 1] = v1;
    }
}

// ---------------------------------------------------------------------------
// knn body (verbatim — proven inside fused_dp_knn).
// ---------------------------------------------------------------------------
__device__ __forceinline__ void knn_body(
        const float* __restrict__ up_points,
        const float* __restrict__ down_points,
        float2* __restrict__ part,
        int bx, int by, int tid, float* smem) {
    float* sx = smem;            // PG*128 = 1536
    float* sy = smem + 1536;
    float* sz = smem + 3072;
    const int base = by * CHUNK;
    for (int t = tid; t < CHUNK; t += 256) {
        int g = base + t;
        int gi = t >> 3, j = t & 7;
        sx[PG * gi + j] = down_points[3 * g];
        sy[PG * gi + j] = down_points[3 * g + 1];
        sz[PG * gi + j] = down_points[3 * g + 2];
    }
    __syncthreads();

    const int m0 = bx * (256 * Q) + tid;
    const int m1 = m0 + 256;
    const float q0x = up_points[3 * m0];
    const float q0y = up_points[3 * m0 + 1];
    const float q0z = up_points[3 * m0 + 2];
    const float q1x = up_points[3 * m1];
    const float q1y = up_points[3 * m1 + 1];
    const float q1z = up_points[3 * m1 + 2];

    float a_gd0 = FLT_MAX, a_gd1 = FLT_MAX, a_gd2 = FLT_MAX;
    int   a_gi0 = 0, a_gi1 = 0, a_gi2 = 0;
    float b_gd0 = FLT_MAX, b_gd1 = FLT_MAX, b_gd2 = FLT_MAX;
    int   b_gi0 = 0, b_gi1 = 0, b_gi2 = 0;

    for (int gi = 0; gi < CHUNK / G; ++gi) {
        float4 x0 = *(const float4*)&sx[PG * gi], x1 = *(const float4*)&sx[PG * gi + 4];
        float4 y0 = *(const float4*)&sy[PG * gi], y1 = *(const float4*)&sy[PG * gi + 4];
        float4 z0 = *(const float4*)&sz[PG * gi], z1 = *(const float4*)&sz[PG * gi + 4];
        float px[G] = {x0.x, x0.y, x0.z, x0.w, x1.x, x1.y, x1.z, x1.w};
        float py[G] = {y0.x, y0.y, y0.z, y0.w, y1.x, y1.y, y1.z, y1.w};
        float pz[G] = {z0.x, z0.y, z0.z, z0.w, z1.x, z1.y, z1.z, z1.w};
        float s0[G], s1[G];
        #pragma unroll
        for (int j = 0; j < G; ++j) {
            float dx0 = q0x - px[j], dy0 = q0y - py[j], dz0 = q0z - pz[j];
            s0[j] = fmaf(dz0, dz0, fmaf(dy0, dy0, dx0 * dx0));
            float dx1 = q1x - px[j], dy1 = q1y - py[j], dz1 = q1z - pz[j];
            s1[j] = fmaf(dz1, dz1, fmaf(dy1, dy1, dx1 * dx1));
        }
        float gm0 = fminf(fminf(fminf(s0[0], s0[1]), fminf(s0[2], s0[3])),
                          fminf(fminf(s0[4], s0[5]), fminf(s0[6], s0[7])));
        float gm1 = fminf(fminf(fminf(s1[0], s1[1]), fminf(s1[2], s1[3])),
                          fminf(fminf(s1[4], s1[5]), fminf(s1[6], s1[7])));
        top3_bl(gm0, gi, a_gd0, a_gd1, a_gd2, a_gi0, a_gi1, a_gi2);
        top3_bl(gm1, gi, b_gd0, b_gd1, b_gd2, b_gi0, b_gi1, b_gi2);
    }

    // exact refine over the 3 winning groups (24 points per query)
    #pragma unroll
    for (int qq = 0; qq < Q; ++qq) {
        const float qx = qq ? q1x : q0x;
        const float qy = qq ? q1y : q0y;
        const float qz = qq ? q1z : q0z;
        int bases[3];
        if (qq == 0) { bases[0] = a_gi0; bases[1] = a_gi1; bases[2] = a_gi2; }
        else         { bases[0] = b_gi0; bases[1] = b_gi1; bases[2] = b_gi2; }
        float D0 = FLT_MAX, D1 = FLT_MAX, D2 = FLT_MAX;
        int I0 = 0, I1 = 0, I2 = 0;
        #pragma unroll
        for (int t = 0; t < 3; ++t) {
            const int gb = bases[t];
            float4 x0 = *(const float4*)&sx[PG * gb], x1 = *(const float4*)&sx[PG * gb + 4];
            float4 y0 = *(const float4*)&sy[PG * gb], y1 = *(const float4*)&sy[PG * gb + 4];
            float4 z0 = *(const float4*)&sz[PG * gb], z1 = *(const float4*)&sz[PG * gb + 4];
            float px[G] = {x0.x, x0.y, x0.z, x0.w, x1.x, x1.y, x1.z, x1.w};
            float py[G] = {y0.x, y0.y, y0.z, y0.w, y1.x, y1.y, y1.z, y1.w};
            float pz[G] = {z0.x, z0.y, z0.z, z0.w, z1.x, z1.y, z1.z, z1.w};
            #pragma unroll
            for (int j = 0; j < G; ++j) {
                float dx = qx - px[j], dy = qy - py[j], dz = qz - pz[j];
                float s = fmaf(dz, dz, fmaf(dy, dy, dx * dx));
                top3_bl(s, base + gb * G + j, D0, D1, D2, I0, I1, I2);
            }
        }
        const int m = qq ? m1 : m0;
        const int o = (by * M_UP + m) * 3;
        part[o]     = make_float2(D0, __int_as_float(I0));
        part[o + 1] = make_float2(D1, __int_as_float(I1));
        part[o + 2] = make_float2(D2, __int_as_float(I2));
    }
}

// ---------------------------------------------------------------------------
// K1+K2 fused (verbatim R11 — measured 67.5us, down-role ~free).
// ---------------------------------------------------------------------------
__global__ __launch_bounds__(256) void fused_dp_knn(
        const float* __restrict__ down_features, const float* __restrict__ wt_down,
        const float* __restrict__ b_down, float* __restrict__ down_f,
        const float* __restrict__ up_points, const float* __restrict__ down_points,
        float2* __restrict__ part) {
    __shared__ __align__(16) float smem[5248];   // max(knn 4608, down 5248) floats
    const int bid = blockIdx.x;
    if (bid < 512) {
        knn_body(up_points, down_points, part, bid & 63, bid >> 6,
                 threadIdx.x, smem);
    } else {
        down_body(down_features, wt_down, b_down, down_f, bid - 512,
                  threadIdx.x, smem);
    }
}

// ---------------------------------------------------------------------------
// K3: fused up-projection + top-3 merge + interpolation + bias + add.
// R12: 64x128 tile, per-thread 4 rows x 8 cols (acc = 8 float4 = 32 VGPR).
// R10 proved the high-intensity tile but died at 1 block/CU; 64 rows gives
// 512 blocks = 2 blocks/CU (8 waves/CU). Per wave per k: 1 b128 (A, 4 rows
// contiguous via transposed-LDS [k][row] stride 72) + 2 b128 (W) = 36 cy of
// the per-CU LDS pipe feeding 16 CU-cy of FMA (R9 ratio was 4.5x; now 2.25x)
// -> k-loop ~37 kcy/CU ~= 15us floor. Bank math: sAT writes r-consecutive ->
// 2-way (free); sAT reads 4 addrs on 2 bank-quads -> 2-way (free); sW reads
// 2-way (free). Epilogue: 4 rows, fully unrolled (static acc indexing).
// ---------------------------------------------------------------------------
__global__ __launch_bounds__(256) void up_fused(
        const float* __restrict__ A, const float* __restrict__ WT,
        const float* __restrict__ bias, const float* __restrict__ down_f,
        const float2* __restrict__ part,
        float* __restrict__ out) {
    __shared__ __align__(16) float sAT[32][72];     // [k][row], 64 rows + pad
    __shared__ __align__(16) float sW[32][128];     // [k][col]
    const int tid = threadIdx.x;
    const int rt4 = (tid >> 4) * 4;                 // first of this thread's 4 rows
    const int ct  = tid & 15;                       // col float4 index (lo half)
    const int rbase = blockIdx.x * 64;

    float4 acc[4][2] = {};
    #pragma unroll 1
    for (int ph = 0; ph < UPC / 32; ++ph) {
        if (ph) __syncthreads();
        {   // stage A transposed: thread (r = tid&63, kq = tid>>6) loads 8 k's
            const int r = tid & 63, kq = tid >> 6;
            const float* Ar = A + (size_t)(rbase + r) * UPC + ph * 32 + kq * 8;
            float4 v0 = *(const float4*)Ar;
            float4 v1 = *(const float4*)(Ar + 4);
            const int k0 = kq * 8;
            sAT[k0 + 0][r] = v0.x; sAT[k0 + 1][r] = v0.y;
            sAT[k0 + 2][r] = v0.z; sAT[k0 + 3][r] = v0.w;
            sAT[k0 + 4][r] = v1.x; sAT[k0 + 5][r] = v1.y;
            sAT[k0 + 6][r] = v1.z; sAT[k0 + 7][r] = v1.w;
        }
        {   // stage W: contiguous float4 copies
            const float4* Wp = (const float4*)(WT + (size_t)ph * 32 * OUTC);
            float4* sW4 = (float4*)&sW[0][0];
            #pragma unroll
            for (int i = 0; i < 4; ++i)
                sW4[tid + i * 256] = Wp[tid + i * 256];
        }
        __syncthreads();
        #pragma unroll 4
        for (int kk = 0; kk < 32; ++kk) {
            float4 a  = *(const float4*)&sAT[kk][rt4];
            float4 w0 = *(const float4*)&sW[kk][ct * 4];
            float4 w1 = *(const float4*)&sW[kk][64 + ct * 4];
            fma4(acc[0][0], a.x, w0); fma4(acc[0][1], a.x, w1);
            fma4(acc[1][0], a.y, w0); fma4(acc[1][1], a.y, w1);
            fma4(acc[2][0], a.z, w0); fma4(acc[2][1], a.z, w1);
            fma4(acc[3][0], a.w, w0); fma4(acc[3][1], a.w, w1);
        }
    }

    const float4 b0 = ((const float4*)bias)[ct];
    const float4 b1 = ((const float4*)bias)[ct + 16];
    const float4* df4 = (const float4*)down_f;
    float4* out4 = (float4*)out;
    #pragma unroll
    for (int i = 0; i < 4; ++i) {                   // full unroll: static acc idx
        const int m = rbase + rt4 + i;
        float D0 = FLT_MAX, D1 = FLT_MAX, D2 = FLT_MAX;
        int I0 = 0, I1 = 0, I2 = 0;
        #pragma unroll
        for (int s = 0; s < NCHUNK; ++s) {
            const float2* p = part + ((size_t)s * M_UP + m) * 3;
            float2 v0 = p[0], v1 = p[1], v2 = p[2];
            top3_bl(v0.x, __float_as_int(v0.y), D0, D1, D2, I0, I1, I2);
            top3_bl(v1.x, __float_as_int(v1.y), D0, D1, D2, I0, I1, I2);
            top3_bl(v2.x, __float_as_int(v2.y), D0, D1, D2, I0, I1, I2);
        }
        float r0 = 1.f / (D0 + 1e-8f);
        float r1 = 1.f / (D1 + 1e-8f);
        float r2 = 1.f / (D2 + 1e-8f);
        float rs = (r0 + r1) + r2;
        float w0 = r0 / rs, w1 = r1 / rs, w2 = r2 / rs;
        float4 f00 = df4[I0 * 32 + ct], f01 = df4[I0 * 32 + ct + 16];
        float4 f10 = df4[I1 * 32 + ct], f11 = df4[I1 * 32 + ct + 16];
        float4 f20 = df4[I2 * 32 + ct], f21 = df4[I2 * 32 + ct + 16];
        float4 res0, res1;
        res0.x = acc[i][0].x + b0.x + fmaf(w0, f00.x, fmaf(w1, f10.x, w2 * f20.x));
        res0.y = acc[i][0].y + b0.y + fmaf(w0, f00.y, fmaf(w1, f10.y, w2 * f20.y));
        res0.z = acc[i][0].z + b0.z + fmaf(w0, f00.z, fmaf(w1, f10.z, w2 * f20.z));
        res0.w = acc[i][0].w + b0.w + fmaf(w0, f00.w, fmaf(w1, f10.w, w2 * f20.w));
        res1.x = acc[i][1].x + b1.x + fmaf(w0, f01.x, fmaf(w1, f11.x, w2 * f21.x));
        res1.y = acc[i][1].y + b1.y + fmaf(w0, f01.y, fmaf(w1, f11.y, w2 * f21.y));
        res1.z = acc[i][1].z + b1.z + fmaf(w0, f01.z, fmaf(w1, f11.z, w2 * f21.z));
        res1.w = acc[i][1].w + b1.w + fmaf(w0, f01.w, fmaf(w1, f11.w, w2 * f21.w));
        out4[m * 32 + ct] = res0;
        out4[m * 32 + ct + 16] = res1;
    }
}

extern "C" void kernel_launch(void* const* d_in, const int* in_sizes, int n_in,
                              void* d_out, int out_size, void* d_ws, size_t ws_size,
                              hipStream_t stream) {
    const float* up_points     = (const float*)d_in[0];
    const float* up_features   = (const float*)d_in[1];
    const float* down_points   = (const float*)d_in[2];
    const float* down_features = (const float*)d_in[3];
    const float* W_up          = (const float*)d_in[4];
    const float* b_up          = (const float*)d_in[5];
    const float* W_down        = (const float*)d_in[6];
    const float* b_down        = (const float*)d_in[7];
    float* out = (float*)d_out;

    float* wt_down = (float*)d_ws;                         // 256*128
    float* wt_up   = wt_down + DOWNC * OUTC;               // 128*128
    float* down_f  = wt_up + UPC * OUTC;                   // 8192*128
    float2* part   = (float2*)(down_f + N_DOWN * OUTC);    // NCHUNK*32768*3 float2
    // total ~10.7 MB (proven footprint)

    transpose_w<<<(DOWNC * OUTC + UPC * OUTC) / 256, 256, 0, stream>>>(
        W_up, W_down, wt_up, wt_down);
    fused_dp_knn<<<768, 256, 0, stream>>>(
        down_features, wt_down, b_down, down_f, up_points, down_points, part);
    up_fused<<<M_UP / 64, 256, 0, stream>>>(
        up_features, wt_up, b_up, down_f, part, out);
}